// Round 6
// baseline (5167.324 us; speedup 1.0000x reference)
//
#include <hip/hip_runtime.h>

// QORNN eval forward: quantized RNN scan, B=256 T=128 I=128 H=1024 O=10.
// Quantized weights/inputs are EXACT in bf16 -> MFMA bf16 with fp32 accum;
// h carried as split bf16 pair (hh+hl, ~17 mantissa bits).
// Persistent scan kernel launched via hipLaunchCooperativeKernel (co-residency
// validated by the runtime -> no deadlock possible). If coop launch is
// rejected, fall back to 128 per-step launches (round-2 proven path).

#define BB 256
#define TT 128
#define II 128
#define HH 1024
#define OO 10
#define EPSF 1e-5f
#define NBLK 256

typedef short bf16x8 __attribute__((ext_vector_type(8)));
typedef float f32x4 __attribute__((ext_vector_type(4)));
typedef unsigned int u32x4 __attribute__((ext_vector_type(4)));

static __device__ __forceinline__ unsigned short f2bf(float f) {
  union { float f; unsigned u; } v; v.f = f;
  unsigned r = v.u + 0x7fffu + ((v.u >> 16) & 1u);
  return (unsigned short)(r >> 16);
}
static __device__ __forceinline__ float bf2f(unsigned short b) {
  union { unsigned u; float f; } v; v.u = ((unsigned)b) << 16;
  return v.f;
}
// jnp.round is round-half-to-EVEN -> rintf (v_rndne_f32), NOT roundf.
static __device__ __forceinline__ float q8(float x) {
  return fminf(fmaxf(__builtin_rintf(x * 128.f), -128.f), 127.f) * 0.0078125f;
}
static __device__ __forceinline__ float q4(float x) {
  return fminf(fmaxf(__builtin_rintf(x * 8.f), -8.f), 7.f) * 0.125f;
}

// ---------------- prep: quantize inputs to bf16, layout [T][B][I] ----------
__global__ __launch_bounds__(256) void k_quant_x(const float* __restrict__ in,
                                                 unsigned short* __restrict__ xq) {
  int idx = blockIdx.x * 256 + threadIdx.x;   // 1,048,576 threads, 4 elems each
  int n = idx * 4;                            // linear over [T][B][I]
  int i = n & (II - 1);
  int rem = n >> 7;                           // t*BB + b
  int b = rem & (BB - 1);
  int t = rem >> 8;
  const float4 v = *reinterpret_cast<const float4*>(in + ((size_t)b * TT + t) * II + i);
  ushort4 o;
  o.x = f2bf(q8(v.x)); o.y = f2bf(q8(v.y)); o.z = f2bf(q8(v.z)); o.w = f2bf(q8(v.w));
  *reinterpret_cast<ushort4*>(xq + n) = o;
}

// -- prep: quantize Wr/Wi to bf16, zero h0, fold norm scales, zero barrier --
__global__ __launch_bounds__(256) void k_prep(
    const float* __restrict__ Wi, const float* __restrict__ Wr,
    const float* __restrict__ bi, const float* __restrict__ br,
    const float* __restrict__ nig, const float* __restrict__ nib,
    const float* __restrict__ nirm, const float* __restrict__ nirv,
    const float* __restrict__ nrg, const float* __restrict__ nrb,
    const float* __restrict__ nrrm, const float* __restrict__ nrrv,
    unsigned short* __restrict__ wiq, unsigned short* __restrict__ wrq,
    unsigned short* __restrict__ hbuf0, float* __restrict__ svec,
    unsigned int* __restrict__ bar) {
  int id = blockIdx.x * 256 + threadIdx.x;
  if (id < 262144) {                       // Wr: 1,048,576 elems, q8
    int e = id * 4;
    const float4 v = *reinterpret_cast<const float4*>(Wr + e);
    ushort4 o;
    o.x = f2bf(q8(v.x)); o.y = f2bf(q8(v.y)); o.z = f2bf(q8(v.z)); o.w = f2bf(q8(v.w));
    *reinterpret_cast<ushort4*>(wrq + e) = o;
  } else if (id < 294912) {                // Wi: 131,072 elems, q4
    int e = (id - 262144) * 4;
    const float4 v = *reinterpret_cast<const float4*>(Wi + e);
    ushort4 o;
    o.x = f2bf(q4(v.x)); o.y = f2bf(q4(v.y)); o.z = f2bf(q4(v.z)); o.w = f2bf(q4(v.w));
    *reinterpret_cast<ushort4*>(wiq + e) = o;
  } else if (id < 360448) {                // zero h0 (1 MB = 65,536 x 16B)
    int e = id - 294912;
    u32x4 z = {0u, 0u, 0u, 0u};
    reinterpret_cast<u32x4*>(hbuf0)[e] = z;
  } else if (id < 361472) {                // folded norm scales
    int j = id - 360448;
    float si = nig[j] / sqrtf(nirv[j] + EPSF);
    float ti = nib[j] - nirm[j] * si;
    float sr = nrg[j] / sqrtf(nrrv[j] + EPSF);
    float tr = nrb[j] - nrrm[j] * sr;
    svec[j] = si;
    svec[HH + j] = sr;
    svec[2 * HH + j] = si * bi[j] + ti + sr * br[j] + tr;
  } else if (id == 361472) {               // zero global-barrier counter
    *bar = 0u;
  }
}

// ---------------- persistent scan: all 128 steps, global spin barrier ------
// grid 256 blocks (b-tile = bid&15, j-tile = bid>>4), 256 thr = 4 waves,
// each wave one 16x16 j-subtile. Cooperative launch -> co-residency
// guaranteed by the runtime -> spin barrier is safe.
__global__ __launch_bounds__(256, 1) void k_scan(
    const unsigned short* __restrict__ xq,   // [T][B][I] bf16 (exact)
    const unsigned short* __restrict__ wiq,  // [H][I]  bf16 (exact)
    const unsigned short* __restrict__ wrq,  // [H][H]  bf16 (exact)
    const float* __restrict__ svec,          // si[H], sr[H], c[H]
    unsigned short* __restrict__ h0,         // buf0: hh[B][H], hl[B][H]
    unsigned short* __restrict__ h1,         // buf1: same layout
    unsigned int* __restrict__ bar) {
  extern __shared__ unsigned char smem[];    // hh tile @0 (32KB), hl @32768
  const int tid = threadIdx.x;
  const int bid = blockIdx.x;
  const int br0 = (bid & 15) * 16;
  const int jbase = (bid >> 4) * 64;
  const int w = tid >> 6, lane = tid & 63;
  const int ar = lane & 15;                  // A-frag row (b within tile)
  const int arsw = (ar & 7) << 4;
  const int khalf = (lane >> 4) * 8;         // A/B frag k-offset
  const int jrow = jbase + w * 16 + ar;      // B-frag row = output col j

  // hoisted per-lane constants
  const float si = svec[jrow];
  const float sr = svec[HH + jrow];
  const float cj = svec[2 * HH + jrow];
  const unsigned short* wrb = wrq + jrow * HH + khalf;
  const unsigned short* wib = wiq + jrow * II + khalf;
  const unsigned short* xp = xq + (size_t)(br0 + ar) * II + khalf;
  const int brow0 = br0 + (lane >> 4) * 4;

  const unsigned short* hr = h0;
  unsigned short* hw = h1;

  for (int t = 0; t < TT; ++t) {
    // ---- stage h pair [16][1024] into LDS, XOR-swizzled ----
#pragma unroll
    for (int r = 0; r < 8; ++r) {
      int e = (r * 256 + tid) * 8;
      int row = e >> 10, col = e & 1023;
      u32x4 vh = *reinterpret_cast<const u32x4*>(hr + (br0 + row) * HH + col);
      u32x4 vl = *reinterpret_cast<const u32x4*>(hr + BB * HH + (br0 + row) * HH + col);
      int byteo = row * 2048 + ((col * 2) ^ ((row & 7) << 4));
      *reinterpret_cast<u32x4*>(smem + byteo) = vh;
      *reinterpret_cast<u32x4*>(smem + 32768 + byteo) = vl;
    }

    // ---- input part, K=128 (no LDS dep -> overlaps stage drain) ----
    f32x4 acc_i = {0.f, 0.f, 0.f, 0.f};
#pragma unroll
    for (int kk = 0; kk < II; kk += 32) {
      bf16x8 ax = *reinterpret_cast<const bf16x8*>(xp + kk);
      bf16x8 bw = *reinterpret_cast<const bf16x8*>(wib + kk);
      acc_i = __builtin_amdgcn_mfma_f32_16x16x32_bf16(ax, bw, acc_i, 0, 0, 0);
    }

    __syncthreads();

    // ---- recurrent part, K=1024, two independent MFMA chains ----
    f32x4 ar1 = {0.f, 0.f, 0.f, 0.f};
    f32x4 ar2 = {0.f, 0.f, 0.f, 0.f};
#pragma unroll 4
    for (int kk = 0; kk < HH; kk += 32) {
      int abyte = ar * 2048 + (((kk + khalf) * 2) ^ arsw);
      bf16x8 ahh = *reinterpret_cast<const bf16x8*>(smem + abyte);
      bf16x8 ahl = *reinterpret_cast<const bf16x8*>(smem + 32768 + abyte);
      bf16x8 bw = *reinterpret_cast<const bf16x8*>(wrb + kk);
      ar1 = __builtin_amdgcn_mfma_f32_16x16x32_bf16(ahh, bw, ar1, 0, 0, 0);
      ar2 = __builtin_amdgcn_mfma_f32_16x16x32_bf16(ahl, bw, ar2, 0, 0, 0);
    }

    // ---- epilogue: tanh, split to bf16 pair, write own slice ----
#pragma unroll
    for (int v = 0; v < 4; ++v) {
      float val = si * acc_i[v] + sr * (ar1[v] + ar2[v]) + cj;
      float hv = tanhf(val);
      unsigned short hb = f2bf(hv);
      float lo = hv - bf2f(hb);
      hw[(size_t)(brow0 + v) * HH + jrow] = hb;
      hw[BB * HH + (size_t)(brow0 + v) * HH + jrow] = f2bf(lo);
    }

    // ---- global barrier (monotonic counter, agent scope) ----
    __threadfence();
    __syncthreads();
    if (tid == 0) {
      __hip_atomic_fetch_add(bar, 1u, __ATOMIC_ACQ_REL, __HIP_MEMORY_SCOPE_AGENT);
      unsigned tgt = (unsigned)(t + 1) * (unsigned)NBLK;
      while (__hip_atomic_load(bar, __ATOMIC_ACQUIRE, __HIP_MEMORY_SCOPE_AGENT) < tgt)
        __builtin_amdgcn_s_sleep(1);
    }
    __syncthreads();

    // swap buffers; advance x pointer
    const unsigned short* tmp = hr; hr = hw; hw = (unsigned short*)tmp;
    xp += BB * II;
  }
}

// -------- fallback: one RNN step per launch (round-2 proven path) ----------
__global__ __launch_bounds__(256) void k_step(
    const unsigned short* __restrict__ xq,
    const unsigned short* __restrict__ wiq,
    const unsigned short* __restrict__ wrq,
    const float* __restrict__ svec,
    const unsigned short* __restrict__ hin,
    unsigned short* __restrict__ hout,
    int t) {
  __shared__ __align__(16) unsigned char smem[65536];
  const int tid = threadIdx.x;
  const int br0 = blockIdx.x * 16;
  const int by = blockIdx.y;

#pragma unroll
  for (int r = 0; r < 8; ++r) {
    int e = (r * 256 + tid) * 8;
    int row = e >> 10, col = e & 1023;
    u32x4 vh = *reinterpret_cast<const u32x4*>(hin + (br0 + row) * HH + col);
    u32x4 vl = *reinterpret_cast<const u32x4*>(hin + BB * HH + (br0 + row) * HH + col);
    int byteo = row * 2048 + ((col * 2) ^ ((row & 7) << 4));
    *reinterpret_cast<u32x4*>(smem + byteo) = vh;
    *reinterpret_cast<u32x4*>(smem + 32768 + byteo) = vl;
  }

  const int w = tid >> 6, lane = tid & 63;
  const int ar = lane & 15;
  const int khalf = (lane >> 4) * 8;
  const int jrow = by * 64 + w * 16 + ar;

  f32x4 acc_i = {0.f, 0.f, 0.f, 0.f};
#pragma unroll
  for (int kk = 0; kk < II; kk += 32) {
    int col0 = kk + khalf;
    bf16x8 ax = *reinterpret_cast<const bf16x8*>(
        xq + ((size_t)t * BB + br0 + ar) * II + col0);
    bf16x8 bw = *reinterpret_cast<const bf16x8*>(wiq + jrow * II + col0);
    acc_i = __builtin_amdgcn_mfma_f32_16x16x32_bf16(ax, bw, acc_i, 0, 0, 0);
  }

  __syncthreads();

  f32x4 ar1 = {0.f, 0.f, 0.f, 0.f};
  f32x4 ar2 = {0.f, 0.f, 0.f, 0.f};
#pragma unroll 4
  for (int kk = 0; kk < HH; kk += 32) {
    int col0 = kk + khalf;
    int abyte = ar * 2048 + ((col0 * 2) ^ ((ar & 7) << 4));
    bf16x8 ahh = *reinterpret_cast<const bf16x8*>(smem + abyte);
    bf16x8 ahl = *reinterpret_cast<const bf16x8*>(smem + 32768 + abyte);
    bf16x8 bw = *reinterpret_cast<const bf16x8*>(wrq + jrow * HH + col0);
    ar1 = __builtin_amdgcn_mfma_f32_16x16x32_bf16(ahh, bw, ar1, 0, 0, 0);
    ar2 = __builtin_amdgcn_mfma_f32_16x16x32_bf16(ahl, bw, ar2, 0, 0, 0);
  }

  const float si = svec[jrow];
  const float sr = svec[HH + jrow];
  const float cj = svec[2 * HH + jrow];
  const int brow0 = br0 + (lane >> 4) * 4;
#pragma unroll
  for (int v = 0; v < 4; ++v) {
    float val = si * acc_i[v] + sr * (ar1[v] + ar2[v]) + cj;
    float hv = tanhf(val);
    unsigned short hb = f2bf(hv);
    float lo = hv - bf2f(hb);
    hout[(size_t)(brow0 + v) * HH + jrow] = hb;
    hout[BB * HH + (size_t)(brow0 + v) * HH + jrow] = f2bf(lo);
  }
}

// ---------------- output: out[b][o] = so*(h . q4(Wo[o])) + to --------------
__global__ __launch_bounds__(256) void k_out(
    const unsigned short* __restrict__ hfin,  // hh[B][H], hl[B][H]
    const float* __restrict__ Wo,
    const float* __restrict__ nog, const float* __restrict__ nob,
    const float* __restrict__ norm_, const float* __restrict__ norv,
    float* __restrict__ out) {
  const int b = blockIdx.x, tid = threadIdx.x;
  __shared__ float lp[4][OO];
  float hv[4];
#pragma unroll
  for (int u = 0; u < 4; ++u) {
    int k = tid * 4 + u;
    hv[u] = bf2f(hfin[b * HH + k]) + bf2f(hfin[BB * HH + b * HH + k]);
  }
  float pacc[OO];
#pragma unroll
  for (int o = 0; o < OO; ++o) {
    float p = 0.f;
#pragma unroll
    for (int u = 0; u < 4; ++u) {
      int k = tid * 4 + u;
      p += hv[u] * q4(Wo[o * HH + k]);
    }
    pacc[o] = p;
  }
#pragma unroll
  for (int o = 0; o < OO; ++o) {
    float p = pacc[o];
    for (int off = 32; off > 0; off >>= 1) p += __shfl_down(p, off);
    if ((tid & 63) == 0) lp[tid >> 6][o] = p;
  }
  __syncthreads();
  if (tid < OO) {
    float s = lp[0][tid] + lp[1][tid] + lp[2][tid] + lp[3][tid];
    float so = nog[tid] / sqrtf(norv[tid] + EPSF);
    float to = nob[tid] - norm_[tid] * so;
    out[b * OO + tid] = s * so + to;
  }
}

// ---------------------------------------------------------------------------
extern "C" void kernel_launch(void* const* d_in, const int* in_sizes, int n_in,
                              void* d_out, int out_size, void* d_ws, size_t ws_size,
                              hipStream_t stream) {
  const float* inputs = (const float*)d_in[0];
  const float* Wi = (const float*)d_in[1];
  const float* bi = (const float*)d_in[2];
  const float* Wr = (const float*)d_in[3];
  const float* br = (const float*)d_in[4];
  const float* Wo = (const float*)d_in[5];
  const float* ni_g = (const float*)d_in[6];
  const float* ni_b = (const float*)d_in[7];
  const float* ni_rm = (const float*)d_in[8];
  const float* ni_rv = (const float*)d_in[9];
  const float* nr_g = (const float*)d_in[10];
  const float* nr_b = (const float*)d_in[11];
  const float* nr_rm = (const float*)d_in[12];
  const float* nr_rv = (const float*)d_in[13];
  const float* no_g = (const float*)d_in[14];
  const float* no_b = (const float*)d_in[15];
  const float* no_rm = (const float*)d_in[16];
  const float* no_rv = (const float*)d_in[17];

  char* ws = (char*)d_ws;
  unsigned short* xq = (unsigned short*)(ws + 0);          // 8,388,608 B
  unsigned short* wiq = (unsigned short*)(ws + 8388608);   //   262,144 B
  unsigned short* wrq = (unsigned short*)(ws + 8650752);   // 2,097,152 B
  unsigned short* hb0 = (unsigned short*)(ws + 10747904);  // 1,048,576 B
  unsigned short* hb1 = (unsigned short*)(ws + 11796480);  // 1,048,576 B
  float* svec = (float*)(ws + 12845056);                   //    12,288 B
  unsigned int* bar = (unsigned int*)(ws + 12857344);      //         4 B

  k_quant_x<<<4096, 256, 0, stream>>>(inputs, xq);
  k_prep<<<1413, 256, 0, stream>>>(Wi, Wr, bi, br, ni_g, ni_b, ni_rm, ni_rv,
                                   nr_g, nr_b, nr_rm, nr_rv, wiq, wrq, hb0, svec, bar);

  // persistent scan via cooperative launch (runtime validates co-residency;
  // fails gracefully instead of deadlocking). 64KB dynamic LDS.
  void* args[] = {(void*)&xq, (void*)&wiq, (void*)&wrq, (void*)&svec,
                  (void*)&hb0, (void*)&hb1, (void*)&bar};
  hipError_t ce = hipLaunchCooperativeKernel((const void*)k_scan, dim3(NBLK),
                                             dim3(256), args, 65536, stream);
  if (ce != hipSuccess) {
    // fallback: 128 per-step launches (proven correct, ~1 ms)
    unsigned short* hb[2] = {hb0, hb1};
    for (int t = 0; t < TT; ++t) {
      k_step<<<dim3(16, 16), 256, 0, stream>>>(xq, wiq, wrq, svec,
                                               hb[t & 1], hb[(t + 1) & 1], t);
    }
  }

  // T=128 even -> final h lives in hb0 (both paths)
  k_out<<<BB, 256, 0, stream>>>(hb0, Wo, no_g, no_b, no_rm, no_rv, (float*)d_out);
}

// Round 7
// 5020.914 us; speedup vs baseline: 1.0292x; 1.0292x over previous
//
#include <hip/hip_runtime.h>

// QORNN eval forward: quantized RNN scan, B=256 T=128 I=128 H=1024 O=10.
// Quantized weights/inputs are EXACT in bf16 -> MFMA bf16 with fp32 accum;
// h carried as split bf16 pair (hh+hl, ~17 mantissa bits).
// Round 7: persistent scan with PER-GROUP DATAFLOW FLAGS instead of a global
// barrier. Only the 16 blocks sharing a b-tile depend on each other; they
// sync via per-block release-flags (own cacheline) + relaxed polling + one
// acquire fence (round-6's acquire-in-spin-loop invalidated L2 continuously
// and cost 37 us/step). Coop launch (co-residency validated); fallback to
// 128 per-step launches if coop launch is rejected.

#define BB 256
#define TT 128
#define II 128
#define HH 1024
#define OO 10
#define EPSF 1e-5f
#define NBLK 256

typedef short bf16x8 __attribute__((ext_vector_type(8)));
typedef float f32x4 __attribute__((ext_vector_type(4)));
typedef unsigned int u32x4 __attribute__((ext_vector_type(4)));

static __device__ __forceinline__ unsigned short f2bf(float f) {
  union { float f; unsigned u; } v; v.f = f;
  unsigned r = v.u + 0x7fffu + ((v.u >> 16) & 1u);
  return (unsigned short)(r >> 16);
}
static __device__ __forceinline__ float bf2f(unsigned short b) {
  union { unsigned u; float f; } v; v.u = ((unsigned)b) << 16;
  return v.f;
}
// jnp.round is round-half-to-EVEN -> rintf (v_rndne_f32), NOT roundf.
static __device__ __forceinline__ float q8(float x) {
  return fminf(fmaxf(__builtin_rintf(x * 128.f), -128.f), 127.f) * 0.0078125f;
}
static __device__ __forceinline__ float q4(float x) {
  return fminf(fmaxf(__builtin_rintf(x * 8.f), -8.f), 7.f) * 0.125f;
}

// ---------------- prep: quantize inputs to bf16, layout [T][B][I] ----------
__global__ __launch_bounds__(256) void k_quant_x(const float* __restrict__ in,
                                                 unsigned short* __restrict__ xq) {
  int idx = blockIdx.x * 256 + threadIdx.x;   // 1,048,576 threads, 4 elems each
  int n = idx * 4;                            // linear over [T][B][I]
  int i = n & (II - 1);
  int rem = n >> 7;                           // t*BB + b
  int b = rem & (BB - 1);
  int t = rem >> 8;
  const float4 v = *reinterpret_cast<const float4*>(in + ((size_t)b * TT + t) * II + i);
  ushort4 o;
  o.x = f2bf(q8(v.x)); o.y = f2bf(q8(v.y)); o.z = f2bf(q8(v.z)); o.w = f2bf(q8(v.w));
  *reinterpret_cast<ushort4*>(xq + n) = o;
}

// -- prep: quantize Wr/Wi to bf16, zero h0, fold norm scales, zero flags ----
__global__ __launch_bounds__(256) void k_prep(
    const float* __restrict__ Wi, const float* __restrict__ Wr,
    const float* __restrict__ bi, const float* __restrict__ br,
    const float* __restrict__ nig, const float* __restrict__ nib,
    const float* __restrict__ nirm, const float* __restrict__ nirv,
    const float* __restrict__ nrg, const float* __restrict__ nrb,
    const float* __restrict__ nrrm, const float* __restrict__ nrrv,
    unsigned short* __restrict__ wiq, unsigned short* __restrict__ wrq,
    unsigned short* __restrict__ hbuf0, float* __restrict__ svec,
    unsigned int* __restrict__ flags) {
  int id = blockIdx.x * 256 + threadIdx.x;
  if (id < 262144) {                       // Wr: 1,048,576 elems, q8
    int e = id * 4;
    const float4 v = *reinterpret_cast<const float4*>(Wr + e);
    ushort4 o;
    o.x = f2bf(q8(v.x)); o.y = f2bf(q8(v.y)); o.z = f2bf(q8(v.z)); o.w = f2bf(q8(v.w));
    *reinterpret_cast<ushort4*>(wrq + e) = o;
  } else if (id < 294912) {                // Wi: 131,072 elems, q4
    int e = (id - 262144) * 4;
    const float4 v = *reinterpret_cast<const float4*>(Wi + e);
    ushort4 o;
    o.x = f2bf(q4(v.x)); o.y = f2bf(q4(v.y)); o.z = f2bf(q4(v.z)); o.w = f2bf(q4(v.w));
    *reinterpret_cast<ushort4*>(wiq + e) = o;
  } else if (id < 360448) {                // zero h0 (1 MB = 65,536 x 16B)
    int e = id - 294912;
    u32x4 z = {0u, 0u, 0u, 0u};
    reinterpret_cast<u32x4*>(hbuf0)[e] = z;
  } else if (id < 361472) {                // folded norm scales
    int j = id - 360448;
    float si = nig[j] / sqrtf(nirv[j] + EPSF);
    float ti = nib[j] - nirm[j] * si;
    float sr = nrg[j] / sqrtf(nrrv[j] + EPSF);
    float tr = nrb[j] - nrrm[j] * sr;
    svec[j] = si;
    svec[HH + j] = sr;
    svec[2 * HH + j] = si * bi[j] + ti + sr * br[j] + tr;
  } else if (id < 369664) {                // zero dataflow flags (8192 words)
    flags[id - 361472] = 0u;
  }
}

// ---------------- persistent scan: all 128 steps, group dataflow sync ------
// grid 256 blocks: bt = bid&15 (b-tile, 16 rows), jt = bid>>4 (j-tile, 64).
// Sync group = the 16 blocks sharing bt (they exchange h slices). Each block
// publishes flag[bt][jt] = t+1 after writing h_{t+1}; consumers poll the 16
// group flags with RELAXED agent loads + one acquire fence (no spin-storm).
__global__ __launch_bounds__(256, 1) void k_scan(
    const unsigned short* __restrict__ xq,   // [T][B][I] bf16 (exact)
    const unsigned short* __restrict__ wiq,  // [H][I]  bf16 (exact)
    const unsigned short* __restrict__ wrq,  // [H][H]  bf16 (exact)
    const float* __restrict__ svec,          // si[H], sr[H], c[H]
    unsigned short* __restrict__ h0,         // buf0: hh[B][H], hl[B][H]
    unsigned short* __restrict__ h1,         // buf1: same layout
    unsigned int* __restrict__ flags) {      // [16 groups][16 blocks][32 pad]
  extern __shared__ unsigned char smem[];    // hh tile @0 (32KB), hl @32768
  const int tid = threadIdx.x;
  const int bid = blockIdx.x;
  const int bt = bid & 15;
  const int jt = bid >> 4;
  const int br0 = bt * 16;
  const int jbase = jt * 64;
  const int w = tid >> 6, lane = tid & 63;
  const int ar = lane & 15;                  // A-frag row (b within tile)
  const int arsw = (ar & 7) << 4;
  const int khalf = (lane >> 4) * 8;         // A/B frag k-offset
  const int jrow = jbase + w * 16 + ar;      // B-frag row = output col j

  // hoisted per-lane constants
  const float si = svec[jrow];
  const float sr = svec[HH + jrow];
  const float cj = svec[2 * HH + jrow];
  const unsigned short* wrb = wrq + jrow * HH + khalf;
  const unsigned short* wib = wiq + jrow * II + khalf;
  const unsigned short* xp = xq + (size_t)(br0 + ar) * II + khalf;
  const int brow0 = br0 + (lane >> 4) * 4;

  unsigned int* pollfl = flags + (size_t)(bt * 16 + (tid & 15)) * 32;
  unsigned int* myfl = flags + (size_t)(bt * 16 + jt) * 32;

  const unsigned short* hr = h0;
  unsigned short* hw = h1;

  for (int t = 0; t < TT; ++t) {
    // ---- dataflow wait: group's h_t published (flags >= t) ----
    // Relaxed polls (no per-poll cache invalidate), single acquire after.
    if (__hip_atomic_load(pollfl, __ATOMIC_RELAXED, __HIP_MEMORY_SCOPE_AGENT) <
        (unsigned)t) {
      do {
        __builtin_amdgcn_s_sleep(2);
      } while (__hip_atomic_load(pollfl, __ATOMIC_RELAXED,
                                 __HIP_MEMORY_SCOPE_AGENT) < (unsigned)t);
    }
    __builtin_amdgcn_fence(__ATOMIC_ACQUIRE, "agent");

    // ---- stage h pair [16][1024] into LDS, XOR-swizzled ----
#pragma unroll
    for (int r = 0; r < 8; ++r) {
      int e = (r * 256 + tid) * 8;
      int row = e >> 10, col = e & 1023;
      u32x4 vh = *reinterpret_cast<const u32x4*>(hr + (br0 + row) * HH + col);
      u32x4 vl = *reinterpret_cast<const u32x4*>(hr + BB * HH + (br0 + row) * HH + col);
      int byteo = row * 2048 + ((col * 2) ^ ((row & 7) << 4));
      *reinterpret_cast<u32x4*>(smem + byteo) = vh;
      *reinterpret_cast<u32x4*>(smem + 32768 + byteo) = vl;
    }

    // ---- input part, K=128 (no LDS dep -> overlaps stage drain) ----
    f32x4 acc_i = {0.f, 0.f, 0.f, 0.f};
#pragma unroll
    for (int kk = 0; kk < II; kk += 32) {
      bf16x8 ax = *reinterpret_cast<const bf16x8*>(xp + kk);
      bf16x8 bw = *reinterpret_cast<const bf16x8*>(wib + kk);
      acc_i = __builtin_amdgcn_mfma_f32_16x16x32_bf16(ax, bw, acc_i, 0, 0, 0);
    }

    __syncthreads();

    // ---- recurrent part, K=1024, two independent MFMA chains ----
    f32x4 ar1 = {0.f, 0.f, 0.f, 0.f};
    f32x4 ar2 = {0.f, 0.f, 0.f, 0.f};
#pragma unroll 4
    for (int kk = 0; kk < HH; kk += 32) {
      int abyte = ar * 2048 + (((kk + khalf) * 2) ^ arsw);
      bf16x8 ahh = *reinterpret_cast<const bf16x8*>(smem + abyte);
      bf16x8 ahl = *reinterpret_cast<const bf16x8*>(smem + 32768 + abyte);
      bf16x8 bw = *reinterpret_cast<const bf16x8*>(wrb + kk);
      ar1 = __builtin_amdgcn_mfma_f32_16x16x32_bf16(ahh, bw, ar1, 0, 0, 0);
      ar2 = __builtin_amdgcn_mfma_f32_16x16x32_bf16(ahl, bw, ar2, 0, 0, 0);
    }

    // ---- epilogue: tanh, split to bf16 pair, write own slice ----
#pragma unroll
    for (int v = 0; v < 4; ++v) {
      float val = si * acc_i[v] + sr * (ar1[v] + ar2[v]) + cj;
      float hv = tanhf(val);
      unsigned short hb = f2bf(hv);
      float lo = hv - bf2f(hb);
      hw[(size_t)(brow0 + v) * HH + jrow] = hb;
      hw[BB * HH + (size_t)(brow0 + v) * HH + jrow] = f2bf(lo);
    }

    // ---- publish: all stores visible, then release flag = t+1 ----
    __threadfence();          // per-thread device release of h stores
    __syncthreads();          // all waves fenced; also guards LDS reuse
    if (tid == 0)
      __hip_atomic_store(myfl, (unsigned)(t + 1), __ATOMIC_RELEASE,
                         __HIP_MEMORY_SCOPE_AGENT);

    // swap buffers; advance x pointer
    const unsigned short* tmp = hr; hr = hw; hw = (unsigned short*)tmp;
    xp += BB * II;
  }
}

// -------- fallback: one RNN step per launch (round-2 proven path) ----------
__global__ __launch_bounds__(256) void k_step(
    const unsigned short* __restrict__ xq,
    const unsigned short* __restrict__ wiq,
    const unsigned short* __restrict__ wrq,
    const float* __restrict__ svec,
    const unsigned short* __restrict__ hin,
    unsigned short* __restrict__ hout,
    int t) {
  __shared__ __align__(16) unsigned char smem[65536];
  const int tid = threadIdx.x;
  const int br0 = blockIdx.x * 16;
  const int by = blockIdx.y;

#pragma unroll
  for (int r = 0; r < 8; ++r) {
    int e = (r * 256 + tid) * 8;
    int row = e >> 10, col = e & 1023;
    u32x4 vh = *reinterpret_cast<const u32x4*>(hin + (br0 + row) * HH + col);
    u32x4 vl = *reinterpret_cast<const u32x4*>(hin + BB * HH + (br0 + row) * HH + col);
    int byteo = row * 2048 + ((col * 2) ^ ((row & 7) << 4));
    *reinterpret_cast<u32x4*>(smem + byteo) = vh;
    *reinterpret_cast<u32x4*>(smem + 32768 + byteo) = vl;
  }

  const int w = tid >> 6, lane = tid & 63;
  const int ar = lane & 15;
  const int khalf = (lane >> 4) * 8;
  const int jrow = by * 64 + w * 16 + ar;

  f32x4 acc_i = {0.f, 0.f, 0.f, 0.f};
#pragma unroll
  for (int kk = 0; kk < II; kk += 32) {
    int col0 = kk + khalf;
    bf16x8 ax = *reinterpret_cast<const bf16x8*>(
        xq + ((size_t)t * BB + br0 + ar) * II + col0);
    bf16x8 bw = *reinterpret_cast<const bf16x8*>(wiq + jrow * II + col0);
    acc_i = __builtin_amdgcn_mfma_f32_16x16x32_bf16(ax, bw, acc_i, 0, 0, 0);
  }

  __syncthreads();

  f32x4 ar1 = {0.f, 0.f, 0.f, 0.f};
  f32x4 ar2 = {0.f, 0.f, 0.f, 0.f};
#pragma unroll 4
  for (int kk = 0; kk < HH; kk += 32) {
    int col0 = kk + khalf;
    int abyte = ar * 2048 + ((col0 * 2) ^ ((ar & 7) << 4));
    bf16x8 ahh = *reinterpret_cast<const bf16x8*>(smem + abyte);
    bf16x8 ahl = *reinterpret_cast<const bf16x8*>(smem + 32768 + abyte);
    bf16x8 bw = *reinterpret_cast<const bf16x8*>(wrq + jrow * HH + col0);
    ar1 = __builtin_amdgcn_mfma_f32_16x16x32_bf16(ahh, bw, ar1, 0, 0, 0);
    ar2 = __builtin_amdgcn_mfma_f32_16x16x32_bf16(ahl, bw, ar2, 0, 0, 0);
  }

  const float si = svec[jrow];
  const float sr = svec[HH + jrow];
  const float cj = svec[2 * HH + jrow];
  const int brow0 = br0 + (lane >> 4) * 4;
#pragma unroll
  for (int v = 0; v < 4; ++v) {
    float val = si * acc_i[v] + sr * (ar1[v] + ar2[v]) + cj;
    float hv = tanhf(val);
    unsigned short hb = f2bf(hv);
    float lo = hv - bf2f(hb);
    hout[(size_t)(brow0 + v) * HH + jrow] = hb;
    hout[BB * HH + (size_t)(brow0 + v) * HH + jrow] = f2bf(lo);
  }
}

// ---------------- output: out[b][o] = so*(h . q4(Wo[o])) + to --------------
__global__ __launch_bounds__(256) void k_out(
    const unsigned short* __restrict__ hfin,  // hh[B][H], hl[B][H]
    const float* __restrict__ Wo,
    const float* __restrict__ nog, const float* __restrict__ nob,
    const float* __restrict__ norm_, const float* __restrict__ norv,
    float* __restrict__ out) {
  const int b = blockIdx.x, tid = threadIdx.x;
  __shared__ float lp[4][OO];
  float hv[4];
#pragma unroll
  for (int u = 0; u < 4; ++u) {
    int k = tid * 4 + u;
    hv[u] = bf2f(hfin[b * HH + k]) + bf2f(hfin[BB * HH + b * HH + k]);
  }
  float pacc[OO];
#pragma unroll
  for (int o = 0; o < OO; ++o) {
    float p = 0.f;
#pragma unroll
    for (int u = 0; u < 4; ++u) {
      int k = tid * 4 + u;
      p += hv[u] * q4(Wo[o * HH + k]);
    }
    pacc[o] = p;
  }
#pragma unroll
  for (int o = 0; o < OO; ++o) {
    float p = pacc[o];
    for (int off = 32; off > 0; off >>= 1) p += __shfl_down(p, off);
    if ((tid & 63) == 0) lp[tid >> 6][o] = p;
  }
  __syncthreads();
  if (tid < OO) {
    float s = lp[0][tid] + lp[1][tid] + lp[2][tid] + lp[3][tid];
    float so = nog[tid] / sqrtf(norv[tid] + EPSF);
    float to = nob[tid] - norm_[tid] * so;
    out[b * OO + tid] = s * so + to;
  }
}

// ---------------------------------------------------------------------------
extern "C" void kernel_launch(void* const* d_in, const int* in_sizes, int n_in,
                              void* d_out, int out_size, void* d_ws, size_t ws_size,
                              hipStream_t stream) {
  const float* inputs = (const float*)d_in[0];
  const float* Wi = (const float*)d_in[1];
  const float* bi = (const float*)d_in[2];
  const float* Wr = (const float*)d_in[3];
  const float* br = (const float*)d_in[4];
  const float* Wo = (const float*)d_in[5];
  const float* ni_g = (const float*)d_in[6];
  const float* ni_b = (const float*)d_in[7];
  const float* ni_rm = (const float*)d_in[8];
  const float* ni_rv = (const float*)d_in[9];
  const float* nr_g = (const float*)d_in[10];
  const float* nr_b = (const float*)d_in[11];
  const float* nr_rm = (const float*)d_in[12];
  const float* nr_rv = (const float*)d_in[13];
  const float* no_g = (const float*)d_in[14];
  const float* no_b = (const float*)d_in[15];
  const float* no_rm = (const float*)d_in[16];
  const float* no_rv = (const float*)d_in[17];

  char* ws = (char*)d_ws;
  unsigned short* xq = (unsigned short*)(ws + 0);          // 8,388,608 B
  unsigned short* wiq = (unsigned short*)(ws + 8388608);   //   262,144 B
  unsigned short* wrq = (unsigned short*)(ws + 8650752);   // 2,097,152 B
  unsigned short* hb0 = (unsigned short*)(ws + 10747904);  // 1,048,576 B
  unsigned short* hb1 = (unsigned short*)(ws + 11796480);  // 1,048,576 B
  float* svec = (float*)(ws + 12845056);                   //    12,288 B
  unsigned int* flags = (unsigned int*)(ws + 12857344);    //    32,768 B

  k_quant_x<<<4096, 256, 0, stream>>>(inputs, xq);
  k_prep<<<1444, 256, 0, stream>>>(Wi, Wr, bi, br, ni_g, ni_b, ni_rm, ni_rv,
                                   nr_g, nr_b, nr_rm, nr_rv, wiq, wrq, hb0, svec, flags);

  // persistent scan via cooperative launch (runtime validates co-residency;
  // fails gracefully instead of deadlocking). 64KB dynamic LDS.
  void* args[] = {(void*)&xq, (void*)&wiq, (void*)&wrq, (void*)&svec,
                  (void*)&hb0, (void*)&hb1, (void*)&flags};
  hipError_t ce = hipLaunchCooperativeKernel((const void*)k_scan, dim3(NBLK),
                                             dim3(256), args, 65536, stream);
  if (ce != hipSuccess) {
    // fallback: 128 per-step launches (proven correct, ~1 ms)
    unsigned short* hb[2] = {hb0, hb1};
    for (int t = 0; t < TT; ++t) {
      k_step<<<dim3(16, 16), 256, 0, stream>>>(xq, wiq, wrq, svec,
                                               hb[t & 1], hb[(t + 1) & 1], t);
    }
  }

  // T=128 even -> final h lives in hb0 (both paths)
  k_out<<<BB, 256, 0, stream>>>(hb0, Wo, no_g, no_b, no_rm, no_rv, (float*)d_out);
}

// Round 10
// 1075.935 us; speedup vs baseline: 4.8026x; 4.6666x over previous
//
#include <hip/hip_runtime.h>

// QORNN eval forward: quantized RNN scan, B=256 T=128 I=128 H=1024 O=10.
// Quantized weights/inputs are EXACT in bf16 -> MFMA bf16 with fp32 accum;
// h carried as split bf16 pair packed in u32 (hh | hl<<16, ~17 mantissa bits).
// Round 10 (= round 8 resubmitted twice; infra failures, never ran):
// persistent scan, dataflow flags, NO per-step cache maintenance:
//  - h written with sc1 (write-through to L3) stores, staged with sc1 loads
//  - flags RELAXED both ways (plain sc1 ops, no buffer_wbl2 / buffer_inv)
//  - release = s_waitcnt vmcnt(0) + syncthreads before flag publish
// Rounds 6/7 spent ~38us/step in per-step buffer_wbl2 (full L2 writeback from
// RELEASE stores) + buffer_inv (L2 invalidate from ACQUIRE fences) evidenced
// by WRITE_SIZE=132MB/dispatch of h traffic reaching HBM.

#define BB 256
#define TT 128
#define II 128
#define HH 1024
#define OO 10
#define EPSF 1e-5f
#define NBLK 256

typedef short bf16x8 __attribute__((ext_vector_type(8)));
typedef float f32x4 __attribute__((ext_vector_type(4)));
typedef unsigned int u32x4 __attribute__((ext_vector_type(4)));
typedef unsigned int u32x2 __attribute__((ext_vector_type(2)));

static __device__ __forceinline__ unsigned short f2bf(float f) {
  union { float f; unsigned u; } v; v.f = f;
  unsigned r = v.u + 0x7fffu + ((v.u >> 16) & 1u);
  return (unsigned short)(r >> 16);
}
static __device__ __forceinline__ float bf2f(unsigned short b) {
  union { unsigned u; float f; } v; v.u = ((unsigned)b) << 16;
  return v.f;
}
// jnp.round is round-half-to-EVEN -> rintf (v_rndne_f32), NOT roundf.
static __device__ __forceinline__ float q8(float x) {
  return fminf(fmaxf(__builtin_rintf(x * 128.f), -128.f), 127.f) * 0.0078125f;
}
static __device__ __forceinline__ float q4(float x) {
  return fminf(fmaxf(__builtin_rintf(x * 8.f), -8.f), 7.f) * 0.125f;
}

// ---------------- prep: quantize inputs to bf16, layout [T][B][I] ----------
__global__ __launch_bounds__(256) void k_quant_x(const float* __restrict__ in,
                                                 unsigned short* __restrict__ xq) {
  int idx = blockIdx.x * 256 + threadIdx.x;   // 1,048,576 threads, 4 elems each
  int n = idx * 4;                            // linear over [T][B][I]
  int i = n & (II - 1);
  int rem = n >> 7;                           // t*BB + b
  int b = rem & (BB - 1);
  int t = rem >> 8;
  const float4 v = *reinterpret_cast<const float4*>(in + ((size_t)b * TT + t) * II + i);
  ushort4 o;
  o.x = f2bf(q8(v.x)); o.y = f2bf(q8(v.y)); o.z = f2bf(q8(v.z)); o.w = f2bf(q8(v.w));
  *reinterpret_cast<ushort4*>(xq + n) = o;
}

// -- prep: quantize Wr/Wi to bf16, zero h0 (u32 pairs), scales, flags -------
__global__ __launch_bounds__(256) void k_prep(
    const float* __restrict__ Wi, const float* __restrict__ Wr,
    const float* __restrict__ bi, const float* __restrict__ br,
    const float* __restrict__ nig, const float* __restrict__ nib,
    const float* __restrict__ nirm, const float* __restrict__ nirv,
    const float* __restrict__ nrg, const float* __restrict__ nrb,
    const float* __restrict__ nrrm, const float* __restrict__ nrrv,
    unsigned short* __restrict__ wiq, unsigned short* __restrict__ wrq,
    unsigned int* __restrict__ hbuf0, float* __restrict__ svec,
    unsigned int* __restrict__ flags) {
  int id = blockIdx.x * 256 + threadIdx.x;
  if (id < 262144) {                       // Wr: 1,048,576 elems, q8
    int e = id * 4;
    const float4 v = *reinterpret_cast<const float4*>(Wr + e);
    ushort4 o;
    o.x = f2bf(q8(v.x)); o.y = f2bf(q8(v.y)); o.z = f2bf(q8(v.z)); o.w = f2bf(q8(v.w));
    *reinterpret_cast<ushort4*>(wrq + e) = o;
  } else if (id < 294912) {                // Wi: 131,072 elems, q4
    int e = (id - 262144) * 4;
    const float4 v = *reinterpret_cast<const float4*>(Wi + e);
    ushort4 o;
    o.x = f2bf(q4(v.x)); o.y = f2bf(q4(v.y)); o.z = f2bf(q4(v.z)); o.w = f2bf(q4(v.w));
    *reinterpret_cast<ushort4*>(wiq + e) = o;
  } else if (id < 311296) {                // zero h0: 16384 x u32x4 = 1 MB
    int e = (id - 294912) * 4;
    u32x4 z = {0u, 0u, 0u, 0u};
    *reinterpret_cast<u32x4*>(hbuf0 + e) = z;
  } else if (id < 312320) {                // folded norm scales
    int j = id - 311296;
    float si = nig[j] / sqrtf(nirv[j] + EPSF);
    float ti = nib[j] - nirm[j] * si;
    float sr = nrg[j] / sqrtf(nrrv[j] + EPSF);
    float tr = nrb[j] - nrrm[j] * sr;
    svec[j] = si;
    svec[HH + j] = sr;
    svec[2 * HH + j] = si * bi[j] + ti + sr * br[j] + tr;
  } else if (id < 320512) {                // zero dataflow flags (8192 words)
    flags[id - 312320] = 0u;
  }
}

// ---------------- persistent scan: all 128 steps, group dataflow sync ------
// grid 256 blocks: bt = bid&15 (b-tile), jt = bid>>4 (j-tile). Sync group =
// 16 blocks sharing bt. h path is sc1 (L3-coherent, no L2 maintenance);
// read-only Wr/Wi/xq stay L2-resident for all 128 steps.
__global__ __launch_bounds__(256, 1) void k_scan(
    const unsigned short* __restrict__ xq,   // [T][B][I] bf16 (exact)
    const unsigned short* __restrict__ wiq,  // [H][I]  bf16 (exact)
    const unsigned short* __restrict__ wrq,  // [H][H]  bf16 (exact)
    const float* __restrict__ svec,          // si[H], sr[H], c[H]
    unsigned int* __restrict__ h0,           // [B][H] u32: hh | hl<<16
    unsigned int* __restrict__ h1,           // same layout
    unsigned int* __restrict__ flags) {      // [16 grp][16 blk][32 pad]
  extern __shared__ unsigned char smem[];    // hh plane @0 (32KB), hl @32768
  const int tid = threadIdx.x;
  const int bid = blockIdx.x;
  const int bt = bid & 15;
  const int jt = bid >> 4;
  const int br0 = bt * 16;
  const int jbase = jt * 64;
  const int w = tid >> 6, lane = tid & 63;
  const int ar = lane & 15;                  // A-frag row (b within tile)
  const int arsw = (ar & 7) << 4;
  const int khalf = (lane >> 4) * 8;         // A/B frag k-offset
  const int jrow = jbase + w * 16 + ar;      // B-frag row = output col j

  const float si = svec[jrow];
  const float sr = svec[HH + jrow];
  const float cj = svec[2 * HH + jrow];
  const unsigned short* wrb = wrq + jrow * HH + khalf;
  const unsigned short* wib = wiq + jrow * II + khalf;
  const unsigned short* xp = xq + (size_t)(br0 + ar) * II + khalf;
  const int brow0 = br0 + (lane >> 4) * 4;

  unsigned int* pollfl = flags + (size_t)(bt * 16 + (tid & 15)) * 32;
  unsigned int* myfl = flags + (size_t)(bt * 16 + jt) * 32;

  const unsigned int* hr = h0;
  unsigned int* hw = h1;

  for (int t = 0; t < TT; ++t) {
    // ---- dataflow wait: RELAXED polls only (no cache maintenance) ----
    if (__hip_atomic_load(pollfl, __ATOMIC_RELAXED, __HIP_MEMORY_SCOPE_AGENT) <
        (unsigned)t) {
      do {
        __builtin_amdgcn_s_sleep(2);
      } while (__hip_atomic_load(pollfl, __ATOMIC_RELAXED,
                                 __HIP_MEMORY_SCOPE_AGENT) < (unsigned)t);
    }
    __syncthreads();   // 16 flags verified collectively before anyone stages

    // ---- input part, K=128 (cached loads, L2-resident) ----
    f32x4 acc_i = {0.f, 0.f, 0.f, 0.f};
#pragma unroll
    for (int kk = 0; kk < II; kk += 32) {
      bf16x8 ax = *reinterpret_cast<const bf16x8*>(xp + kk);
      bf16x8 bw = *reinterpret_cast<const bf16x8*>(wib + kk);
      acc_i = __builtin_amdgcn_mfma_f32_16x16x32_bf16(ax, bw, acc_i, 0, 0, 0);
    }

    // ---- stage h: 16 sc1 dwordx4 loads, all in flight, one drain ----
    u32x4 st[16];
#pragma unroll
    for (int it = 0; it < 16; ++it) {
      const unsigned int* p = hr + (size_t)(br0 + it) * HH + tid * 4;
      asm volatile("global_load_dwordx4 %0, %1, off sc1"
                   : "=&v"(st[it]) : "v"(p) : "memory");
    }
    asm volatile("s_waitcnt vmcnt(0)" ::: "memory");
    __builtin_amdgcn_sched_barrier(0);

    // unpack pairs -> hh/hl planes in LDS, XOR-swizzled (row stride 2048B)
#pragma unroll
    for (int it = 0; it < 16; ++it) {
      unsigned hh01 = __builtin_amdgcn_perm(st[it][1], st[it][0], 0x05040100u);
      unsigned hh23 = __builtin_amdgcn_perm(st[it][3], st[it][2], 0x05040100u);
      unsigned hl01 = __builtin_amdgcn_perm(st[it][1], st[it][0], 0x07060302u);
      unsigned hl23 = __builtin_amdgcn_perm(st[it][3], st[it][2], 0x07060302u);
      int byteo = it * 2048 + ((tid * 8) ^ ((it & 7) << 4));
      u32x2 vh = {hh01, hh23};
      u32x2 vl = {hl01, hl23};
      *reinterpret_cast<u32x2*>(smem + byteo) = vh;
      *reinterpret_cast<u32x2*>(smem + 32768 + byteo) = vl;
    }

    __syncthreads();

    // ---- recurrent part, K=1024, two independent MFMA chains ----
    f32x4 ar1 = {0.f, 0.f, 0.f, 0.f};
    f32x4 ar2 = {0.f, 0.f, 0.f, 0.f};
#pragma unroll 4
    for (int kk = 0; kk < HH; kk += 32) {
      int abyte = ar * 2048 + (((kk + khalf) * 2) ^ arsw);
      bf16x8 ahh = *reinterpret_cast<const bf16x8*>(smem + abyte);
      bf16x8 ahl = *reinterpret_cast<const bf16x8*>(smem + 32768 + abyte);
      bf16x8 bw = *reinterpret_cast<const bf16x8*>(wrb + kk);
      ar1 = __builtin_amdgcn_mfma_f32_16x16x32_bf16(ahh, bw, ar1, 0, 0, 0);
      ar2 = __builtin_amdgcn_mfma_f32_16x16x32_bf16(ahl, bw, ar2, 0, 0, 0);
    }

    // ---- epilogue: tanh, pack pair, sc1 write-through store ----
#pragma unroll
    for (int v = 0; v < 4; ++v) {
      float val = si * acc_i[v] + sr * (ar1[v] + ar2[v]) + cj;
      float hv = tanhf(val);
      unsigned hb = f2bf(hv);
      float lo = hv - bf2f((unsigned short)hb);
      unsigned pk = hb | ((unsigned)f2bf(lo) << 16);
      unsigned int* dst = hw + (size_t)(brow0 + v) * HH + jrow;
      asm volatile("global_store_dword %0, %1, off sc1"
                   :: "v"(dst), "v"(pk) : "memory");
    }

    // ---- publish: drain sc1 stores, converge, relaxed flag store ----
    asm volatile("s_waitcnt vmcnt(0)" ::: "memory");
    __syncthreads();
    if (tid == 0)
      __hip_atomic_store(myfl, (unsigned)(t + 1), __ATOMIC_RELAXED,
                         __HIP_MEMORY_SCOPE_AGENT);

    const unsigned int* tmp = hr; hr = hw; hw = (unsigned int*)tmp;
    xp += BB * II;
  }
}

// -------- fallback: one RNN step per launch (kernel-boundary coherence) ----
__global__ __launch_bounds__(256) void k_step(
    const unsigned short* __restrict__ xq,
    const unsigned short* __restrict__ wiq,
    const unsigned short* __restrict__ wrq,
    const float* __restrict__ svec,
    const unsigned int* __restrict__ hin,
    unsigned int* __restrict__ hout,
    int t) {
  __shared__ __align__(16) unsigned char smem[65536];
  const int tid = threadIdx.x;
  const int br0 = blockIdx.x * 16;
  const int by = blockIdx.y;

#pragma unroll
  for (int it = 0; it < 16; ++it) {
    u32x4 p4 = *reinterpret_cast<const u32x4*>(hin + (size_t)(br0 + it) * HH + tid * 4);
    unsigned hh01 = __builtin_amdgcn_perm(p4[1], p4[0], 0x05040100u);
    unsigned hh23 = __builtin_amdgcn_perm(p4[3], p4[2], 0x05040100u);
    unsigned hl01 = __builtin_amdgcn_perm(p4[1], p4[0], 0x07060302u);
    unsigned hl23 = __builtin_amdgcn_perm(p4[3], p4[2], 0x07060302u);
    int byteo = it * 2048 + ((tid * 8) ^ ((it & 7) << 4));
    u32x2 vh = {hh01, hh23};
    u32x2 vl = {hl01, hl23};
    *reinterpret_cast<u32x2*>(smem + byteo) = vh;
    *reinterpret_cast<u32x2*>(smem + 32768 + byteo) = vl;
  }

  const int w = tid >> 6, lane = tid & 63;
  const int ar = lane & 15;
  const int khalf = (lane >> 4) * 8;
  const int jrow = by * 64 + w * 16 + ar;

  f32x4 acc_i = {0.f, 0.f, 0.f, 0.f};
#pragma unroll
  for (int kk = 0; kk < II; kk += 32) {
    int col0 = kk + khalf;
    bf16x8 ax = *reinterpret_cast<const bf16x8*>(
        xq + ((size_t)t * BB + br0 + ar) * II + col0);
    bf16x8 bw = *reinterpret_cast<const bf16x8*>(wiq + jrow * II + col0);
    acc_i = __builtin_amdgcn_mfma_f32_16x16x32_bf16(ax, bw, acc_i, 0, 0, 0);
  }

  __syncthreads();

  f32x4 ar1 = {0.f, 0.f, 0.f, 0.f};
  f32x4 ar2 = {0.f, 0.f, 0.f, 0.f};
#pragma unroll 4
  for (int kk = 0; kk < HH; kk += 32) {
    int col0 = kk + khalf;
    int abyte = ar * 2048 + ((col0 * 2) ^ ((ar & 7) << 4));
    bf16x8 ahh = *reinterpret_cast<const bf16x8*>(smem + abyte);
    bf16x8 ahl = *reinterpret_cast<const bf16x8*>(smem + 32768 + abyte);
    bf16x8 bw = *reinterpret_cast<const bf16x8*>(wrq + jrow * HH + col0);
    ar1 = __builtin_amdgcn_mfma_f32_16x16x32_bf16(ahh, bw, ar1, 0, 0, 0);
    ar2 = __builtin_amdgcn_mfma_f32_16x16x32_bf16(ahl, bw, ar2, 0, 0, 0);
  }

  const float si = svec[jrow];
  const float sr = svec[HH + jrow];
  const float cj = svec[2 * HH + jrow];
  const int brow0 = br0 + (lane >> 4) * 4;
#pragma unroll
  for (int v = 0; v < 4; ++v) {
    float val = si * acc_i[v] + sr * (ar1[v] + ar2[v]) + cj;
    float hv = tanhf(val);
    unsigned hb = f2bf(hv);
    float lo = hv - bf2f((unsigned short)hb);
    hout[(size_t)(brow0 + v) * HH + jrow] = hb | ((unsigned)f2bf(lo) << 16);
  }
}

// ---------------- output: out[b][o] = so*(h . q4(Wo[o])) + to --------------
__global__ __launch_bounds__(256) void k_out(
    const unsigned int* __restrict__ hfin,    // [B][H] u32 pairs
    const float* __restrict__ Wo,
    const float* __restrict__ nog, const float* __restrict__ nob,
    const float* __restrict__ norm_, const float* __restrict__ norv,
    float* __restrict__ out) {
  const int b = blockIdx.x, tid = threadIdx.x;
  __shared__ float lp[4][OO];
  u32x4 hp = *reinterpret_cast<const u32x4*>(hfin + (size_t)b * HH + tid * 4);
  float hv[4];
#pragma unroll
  for (int u = 0; u < 4; ++u)
    hv[u] = bf2f((unsigned short)(hp[u] & 0xffffu)) +
            bf2f((unsigned short)(hp[u] >> 16));
  float pacc[OO];
#pragma unroll
  for (int o = 0; o < OO; ++o) {
    float p = 0.f;
#pragma unroll
    for (int u = 0; u < 4; ++u) {
      int k = tid * 4 + u;
      p += hv[u] * q4(Wo[o * HH + k]);
    }
    pacc[o] = p;
  }
#pragma unroll
  for (int o = 0; o < OO; ++o) {
    float p = pacc[o];
    for (int off = 32; off > 0; off >>= 1) p += __shfl_down(p, off);
    if ((tid & 63) == 0) lp[tid >> 6][o] = p;
  }
  __syncthreads();
  if (tid < OO) {
    float s = lp[0][tid] + lp[1][tid] + lp[2][tid] + lp[3][tid];
    float so = nog[tid] / sqrtf(norv[tid] + EPSF);
    float to = nob[tid] - norm_[tid] * so;
    out[b * OO + tid] = s * so + to;
  }
}

// ---------------------------------------------------------------------------
extern "C" void kernel_launch(void* const* d_in, const int* in_sizes, int n_in,
                              void* d_out, int out_size, void* d_ws, size_t ws_size,
                              hipStream_t stream) {
  const float* inputs = (const float*)d_in[0];
  const float* Wi = (const float*)d_in[1];
  const float* bi = (const float*)d_in[2];
  const float* Wr = (const float*)d_in[3];
  const float* br = (const float*)d_in[4];
  const float* Wo = (const float*)d_in[5];
  const float* ni_g = (const float*)d_in[6];
  const float* ni_b = (const float*)d_in[7];
  const float* ni_rm = (const float*)d_in[8];
  const float* ni_rv = (const float*)d_in[9];
  const float* nr_g = (const float*)d_in[10];
  const float* nr_b = (const float*)d_in[11];
  const float* nr_rm = (const float*)d_in[12];
  const float* nr_rv = (const float*)d_in[13];
  const float* no_g = (const float*)d_in[14];
  const float* no_b = (const float*)d_in[15];
  const float* no_rm = (const float*)d_in[16];
  const float* no_rv = (const float*)d_in[17];

  char* ws = (char*)d_ws;
  unsigned short* xq = (unsigned short*)(ws + 0);          // 8,388,608 B
  unsigned short* wiq = (unsigned short*)(ws + 8388608);   //   262,144 B
  unsigned short* wrq = (unsigned short*)(ws + 8650752);   // 2,097,152 B
  unsigned int* hb0 = (unsigned int*)(ws + 10747904);      // 1,048,576 B
  unsigned int* hb1 = (unsigned int*)(ws + 11796480);      // 1,048,576 B
  float* svec = (float*)(ws + 12845056);                   //    12,288 B
  unsigned int* flags = (unsigned int*)(ws + 12857344);    //    32,768 B

  k_quant_x<<<4096, 256, 0, stream>>>(inputs, xq);
  k_prep<<<1252, 256, 0, stream>>>(Wi, Wr, bi, br, ni_g, ni_b, ni_rm, ni_rv,
                                   nr_g, nr_b, nr_rm, nr_rv, wiq, wrq, hb0, svec, flags);

  // persistent scan via cooperative launch (runtime validates co-residency;
  // fails gracefully instead of deadlocking). 64KB dynamic LDS.
  void* args[] = {(void*)&xq, (void*)&wiq, (void*)&wrq, (void*)&svec,
                  (void*)&hb0, (void*)&hb1, (void*)&flags};
  hipError_t ce = hipLaunchCooperativeKernel((const void*)k_scan, dim3(NBLK),
                                             dim3(256), args, 65536, stream);
  if (ce != hipSuccess) {
    // fallback: 128 per-step launches (proven correct, ~1 ms)
    unsigned int* hb[2] = {hb0, hb1};
    for (int t = 0; t < TT; ++t) {
      k_step<<<dim3(16, 16), 256, 0, stream>>>(xq, wiq, wrq, svec,
                                               hb[t & 1], hb[(t + 1) & 1], t);
    }
  }

  // T=128 even -> final h lives in hb0 (both paths)
  k_out<<<BB, 256, 0, stream>>>(hb0, Wo, no_g, no_b, no_rm, no_rv, (float*)d_out);
}